// Round 10
// baseline (225.304 us; speedup 1.0000x reference)
//
#include <hip/hip_runtime.h>
#include <hip/hip_bf16.h>

// ---------------------------------------------------------------------------
// GCN 3-layer, N=50000, E=800000, D=64, fp32 in/out.
// R10: R8 structure (measured best, 198.6us) + degree-binned node
// permutation for the agg. R9's plane-split regressed: gather traffic is
// COMPULSORY cross-XCD (each XCD touches ~all rows: 8 x table size, matches
// R5's 90MB FETCH for a 12.8MB table) — L2 residency can't help. What can:
// divergence. A wave co-schedules 4 node-groups and runs max(deg of 4)
// (~20 vs mean 16 = 25% waste); perm orders nodes by degree so groups are
// uniform. MFMA gemm (R8), bucket adjacency + XCD-partitioned fill (R3/R4).
// ---------------------------------------------------------------------------

#define CAP 64
#define EDGE_CHUNK 1024

typedef __attribute__((ext_vector_type(8))) short bf16x8;
typedef __attribute__((ext_vector_type(4))) float f32x4;

// --- pack two fp32 -> bf16x2 (RNE) ----------------------------------------
__device__ inline unsigned pack_bf16(float a, float b) {
    union { float f; unsigned i; } ua, ub;
    ua.f = a; ub.f = b;
    unsigned x = (ua.i + 0x7fffu + ((ua.i >> 16) & 1u)) >> 16;
    unsigned y = (ub.i + 0x7fffu + ((ub.i >> 16) & 1u)) >> 16;
    return x | (y << 16);
}
__device__ inline unsigned short to_bf16(float a) {
    union { float f; unsigned i; } u; u.f = a;
    return (unsigned short)((u.i + 0x7fffu + ((u.i >> 16) & 1u)) >> 16);
}
// --- accumulate bf16x2 (packed uint) into two floats ----------------------
__device__ inline void acc_bf16x2(unsigned u, float& a, float& b) {
    union { unsigned i; float f; } lo, hi;
    lo.i = u << 16;
    hi.i = u & 0xffff0000u;
    a += lo.f; b += hi.f;
}

// --- fused count+place: slot = atomicAdd(cnt), XCD-partitioned by dst -----
__global__ void fill_kernel(const int* __restrict__ src, const int* __restrict__ dst,
                            int* __restrict__ cnt, int* __restrict__ adj,
                            int E, int npc) {
    int cls = blockIdx.x & 7;          // -> XCD (round-robin heuristic)
    int base = (blockIdx.x >> 3) * EDGE_CHUNK;
    int end = min(base + EDGE_CHUNK, E);
    int lo = cls * npc, hi = lo + npc;
    for (int e = base + threadIdx.x; e < end; e += blockDim.x) {
        int d = dst[e];
        if (d >= lo && d < hi) {
            int p = atomicAdd(&cnt[d], 1);
            adj[(size_t)d * CAP + p] = src[e];
        }
    }
}

// --- degree histogram (64 bins, LDS-staged) -------------------------------
__global__ void hist_kernel(const int* __restrict__ cnt, int* __restrict__ hist, int n) {
    __shared__ int lh[64];
    int t = threadIdx.x;
    if (t < 64) lh[t] = 0;
    __syncthreads();
    int i = blockIdx.x * blockDim.x + t;
    if (i < n) atomicAdd(&lh[min(cnt[i], 63)], 1);
    __syncthreads();
    if (t < 64 && lh[t]) atomicAdd(&hist[t], lh[t]);
}

// --- exclusive scan of 64 bins (one wave) ---------------------------------
__global__ void binscan_kernel(const int* __restrict__ hist, int* __restrict__ binpos) {
    int lane = threadIdx.x & 63;
    int v = hist[lane];
    int orig = v;
#pragma unroll
    for (int off = 1; off < 64; off <<= 1) {
        int u = __shfl_up(v, off);
        if (lane >= off) v += u;
    }
    binpos[lane] = v - orig;
}

// --- place nodes into degree-sorted perm ----------------------------------
__global__ void place_kernel(const int* __restrict__ cnt, int* __restrict__ binpos,
                             int* __restrict__ perm, int n) {
    __shared__ int lh[64];
    __shared__ int lbase[64];
    int t = threadIdx.x;
    if (t < 64) lh[t] = 0;
    __syncthreads();
    int i = blockIdx.x * blockDim.x + t;
    int d = 0, lp = 0;
    bool ok = (i < n);
    if (ok) {
        d = min(cnt[i], 63);
        lp = atomicAdd(&lh[d], 1);
    }
    __syncthreads();
    if (t < 64) lbase[t] = lh[t] ? atomicAdd(&binpos[t], lh[t]) : 0;
    __syncthreads();
    if (ok) perm[lbase[d] + lp] = i;
}

// --- g(bf16) = dinv ⊙ (in @ W) via MFMA; 64 rows/block, 4 waves -----------
__global__ __launch_bounds__(256) void gemm_kernel(const float* __restrict__ in,
                                                   const float* __restrict__ W,
                                                   const int* __restrict__ cnt,
                                                   unsigned short* __restrict__ g, int n) {
    __shared__ unsigned short Wb[512 * 8];  // B-frags: 8 (s,c) x 64 lanes x 8 bf16
    int t = threadIdx.x;

    // ---- stage W into B-fragment order (bf16) ----
#pragma unroll
    for (int e0 = 0; e0 < 2; e0++) {
        int e = t + e0 * 256;          // frag index 0..511
        int sc = e >> 6;               // s*4 + c
        int l  = e & 63;               // target lane
        int s = sc >> 2, c = sc & 3;
        int nn = c * 16 + (l & 15);
        int kb = s * 32 + (l >> 4) * 8;
        const float* wp = &W[(size_t)kb * 64 + nn];
        unsigned q0 = pack_bf16(wp[0 * 64], wp[1 * 64]);
        unsigned q1 = pack_bf16(wp[2 * 64], wp[3 * 64]);
        unsigned q2 = pack_bf16(wp[4 * 64], wp[5 * 64]);
        unsigned q3 = pack_bf16(wp[6 * 64], wp[7 * 64]);
        *(uint4*)&Wb[e * 8] = make_uint4(q0, q1, q2, q3);
    }

    int wv = t >> 6;
    int lane = t & 63;
    int quad = lane >> 4;
    int m16 = lane & 15;

    // ---- A fragments: row m16 of this wave's 16-row slab, k per quad ----
    int rowA = blockIdx.x * 64 + wv * 16 + m16;
    union { bf16x8 v; uint4 u; } a0, a1;
    {
        float4 f0 = make_float4(0, 0, 0, 0), f1 = f0, f2 = f0, f3 = f0;
        if (rowA < n) {
            const float* rp = &in[(size_t)rowA * 64];
            f0 = *(const float4*)&rp[quad * 8];
            f1 = *(const float4*)&rp[quad * 8 + 4];
            f2 = *(const float4*)&rp[32 + quad * 8];
            f3 = *(const float4*)&rp[32 + quad * 8 + 4];
        }
        a0.u = make_uint4(pack_bf16(f0.x, f0.y), pack_bf16(f0.z, f0.w),
                          pack_bf16(f1.x, f1.y), pack_bf16(f1.z, f1.w));
        a1.u = make_uint4(pack_bf16(f2.x, f2.y), pack_bf16(f2.z, f2.w),
                          pack_bf16(f3.x, f3.y), pack_bf16(f3.z, f3.w));
    }
    __syncthreads();

    // ---- 8 MFMAs: 4 col-tiles x 2 k-steps ----
    f32x4 acc[4];
#pragma unroll
    for (int c = 0; c < 4; c++) {
        bf16x8 b0 = *(const bf16x8*)&Wb[((size_t)(0 * 4 + c) * 64 + lane) * 8];
        bf16x8 b1 = *(const bf16x8*)&Wb[((size_t)(1 * 4 + c) * 64 + lane) * 8];
        f32x4 z = {0.f, 0.f, 0.f, 0.f};
        z = __builtin_amdgcn_mfma_f32_16x16x32_bf16(a0.v, b0, z, 0, 0, 0);
        z = __builtin_amdgcn_mfma_f32_16x16x32_bf16(a1.v, b1, z, 0, 0, 0);
        acc[c] = z;
    }

    // ---- epilogue: scale by dinv[row], store bf16 ----
    int rowbase = blockIdx.x * 64 + wv * 16 + quad * 4;
    float dv[4];
#pragma unroll
    for (int r = 0; r < 4; r++) {
        int row = rowbase + r;
        dv[r] = (row < n) ? rsqrtf((float)(cnt[row] + 1)) : 0.f;
    }
#pragma unroll
    for (int c = 0; c < 4; c++) {
#pragma unroll
        for (int r = 0; r < 4; r++) {
            int row = rowbase + r;
            if (row < n)
                g[(size_t)row * 64 + c * 16 + m16] = to_bf16(acc[c][r] * dv[r]);
        }
    }
}

// --- aggregation (R8 form + perm): 16 lanes/node (uint2), unroll-8 --------
// Nodes visited in degree-sorted order: co-scheduled groups have ~equal deg.
template <int MODE>
__global__ __launch_bounds__(256) void agg_kernel(const unsigned short* __restrict__ g,
                                                  const int* __restrict__ cnt,
                                                  const int* __restrict__ adj,
                                                  const int* __restrict__ perm,
                                                  const float* __restrict__ bias,
                                                  const float* __restrict__ res,
                                                  float* __restrict__ out, int n) {
    int t = threadIdx.x;
    int lg = t & 15;
    int slot = blockIdx.x * 16 + (t >> 4);
    if (slot >= n) return;
    int i = perm[slot];
    int deg = cnt[i];
    const int* lst = adj + (size_t)i * CAP;
    const int c4 = lg * 4;
    float ax = 0.f, ay = 0.f, az = 0.f, aw = 0.f;
    {   // self loop
        uint2 v = *(const uint2*)&g[(size_t)i * 64 + c4];
        acc_bf16x2(v.x, ax, ay);
        acc_bf16x2(v.y, az, aw);
    }
    int k = 0;
    for (; k + 8 <= deg; k += 8) {
        int j0 = lst[k], j1 = lst[k + 1], j2 = lst[k + 2], j3 = lst[k + 3];
        int j4 = lst[k + 4], j5 = lst[k + 5], j6 = lst[k + 6], j7 = lst[k + 7];
        uint2 v0 = *(const uint2*)&g[(size_t)j0 * 64 + c4];
        uint2 v1 = *(const uint2*)&g[(size_t)j1 * 64 + c4];
        uint2 v2 = *(const uint2*)&g[(size_t)j2 * 64 + c4];
        uint2 v3 = *(const uint2*)&g[(size_t)j3 * 64 + c4];
        uint2 v4 = *(const uint2*)&g[(size_t)j4 * 64 + c4];
        uint2 v5 = *(const uint2*)&g[(size_t)j5 * 64 + c4];
        uint2 v6 = *(const uint2*)&g[(size_t)j6 * 64 + c4];
        uint2 v7 = *(const uint2*)&g[(size_t)j7 * 64 + c4];
        acc_bf16x2(v0.x, ax, ay); acc_bf16x2(v0.y, az, aw);
        acc_bf16x2(v1.x, ax, ay); acc_bf16x2(v1.y, az, aw);
        acc_bf16x2(v2.x, ax, ay); acc_bf16x2(v2.y, az, aw);
        acc_bf16x2(v3.x, ax, ay); acc_bf16x2(v3.y, az, aw);
        acc_bf16x2(v4.x, ax, ay); acc_bf16x2(v4.y, az, aw);
        acc_bf16x2(v5.x, ax, ay); acc_bf16x2(v5.y, az, aw);
        acc_bf16x2(v6.x, ax, ay); acc_bf16x2(v6.y, az, aw);
        acc_bf16x2(v7.x, ax, ay); acc_bf16x2(v7.y, az, aw);
    }
    if (k + 4 <= deg) {
        int j0 = lst[k], j1 = lst[k + 1], j2 = lst[k + 2], j3 = lst[k + 3];
        uint2 v0 = *(const uint2*)&g[(size_t)j0 * 64 + c4];
        uint2 v1 = *(const uint2*)&g[(size_t)j1 * 64 + c4];
        uint2 v2 = *(const uint2*)&g[(size_t)j2 * 64 + c4];
        uint2 v3 = *(const uint2*)&g[(size_t)j3 * 64 + c4];
        acc_bf16x2(v0.x, ax, ay); acc_bf16x2(v0.y, az, aw);
        acc_bf16x2(v1.x, ax, ay); acc_bf16x2(v1.y, az, aw);
        acc_bf16x2(v2.x, ax, ay); acc_bf16x2(v2.y, az, aw);
        acc_bf16x2(v3.x, ax, ay); acc_bf16x2(v3.y, az, aw);
        k += 4;
    }
    for (; k < deg; k++) {
        uint2 v = *(const uint2*)&g[(size_t)lst[k] * 64 + c4];
        acc_bf16x2(v.x, ax, ay);
        acc_bf16x2(v.y, az, aw);
    }
    float dv = rsqrtf((float)(deg + 1));
    float4 bb = *(const float4*)&bias[c4];
    float4 v;
    v.x = dv * ax + bb.x;
    v.y = dv * ay + bb.y;
    v.z = dv * az + bb.z;
    v.w = dv * aw + bb.w;
    if (MODE == 0) {
        float4 r = *(const float4*)&res[(size_t)i * 64 + c4];
        v.x = fmaxf(v.x, 0.f) + r.x;
        v.y = fmaxf(v.y, 0.f) + r.y;
        v.z = fmaxf(v.z, 0.f) + r.z;
        v.w = fmaxf(v.w, 0.f) + r.w;
    }
    *(float4*)&out[(size_t)i * 64 + c4] = v;
}

extern "C" void kernel_launch(void* const* d_in, const int* in_sizes, int n_in,
                              void* d_out, int out_size, void* d_ws, size_t ws_size,
                              hipStream_t stream) {
    const float* x  = (const float*)d_in[0];
    const int*   ei = (const int*)d_in[1];
    const float* W1 = (const float*)d_in[2];
    const float* b1 = (const float*)d_in[3];
    const float* W2 = (const float*)d_in[4];
    const float* b2 = (const float*)d_in[5];
    const float* W3 = (const float*)d_in[6];
    const float* b3 = (const float*)d_in[7];
    float* out = (float*)d_out;

    const int N = in_sizes[0] / 64;
    const int E = in_sizes[1] / 2;
    const int* src = ei;
    const int* dst = ei + E;
    const int npc = (N + 7) / 8;
    const int nEdgeChunks = (E + EDGE_CHUNK - 1) / EDGE_CHUNK;
    const int cntSlots = ((N + 63) / 64) * 64;

    // workspace layout (cnt + hist + binpos contiguous -> one memset)
    char* p = (char*)d_ws;
    int*            cnt    = (int*)p;            p += (size_t)cntSlots * 4;
    int*            hist   = (int*)p;            p += 64 * 4;
    int*            binpos = (int*)p;            p += 64 * 4;
    int*            perm   = (int*)p;            p += (size_t)N * 4;
    int*            adj    = (int*)p;            p += ((size_t)N + 1) * CAP * 4;
    unsigned short* g      = (unsigned short*)p; p += (size_t)N * 64 * 2;
    float*          h      = (float*)p;          p += (size_t)N * 64 * 4;

    const int aggBlocks  = (N + 15) / 16;
    const int gemmBlocks = (N + 63) / 64;
    const int nBlocks    = (N + 255) / 256;

    // --- graph build: bucket adjacency + degree-sorted perm ---
    hipMemsetAsync(cnt, 0, ((size_t)cntSlots + 128) * 4, stream);
    fill_kernel<<<nEdgeChunks * 8, 256, 0, stream>>>(src, dst, cnt, adj, E, npc);
    hist_kernel<<<nBlocks, 256, 0, stream>>>(cnt, hist, N);
    binscan_kernel<<<1, 64, 0, stream>>>(hist, binpos);
    place_kernel<<<nBlocks, 256, 0, stream>>>(cnt, binpos, perm, N);

    // --- layer 1: h = relu(agg(dinv⊙(x@W1))) + x ---
    gemm_kernel<<<gemmBlocks, 256, 0, stream>>>(x, W1, cnt, g, N);
    agg_kernel<0><<<aggBlocks, 256, 0, stream>>>(g, cnt, adj, perm, b1, x, h, N);

    // --- layer 2: h = relu(agg(dinv⊙(h@W2))) + h ---
    gemm_kernel<<<gemmBlocks, 256, 0, stream>>>(h, W2, cnt, g, N);
    agg_kernel<0><<<aggBlocks, 256, 0, stream>>>(g, cnt, adj, perm, b2, h, h, N);

    // --- layer 3: out = agg(dinv⊙(h@W3)) ---
    gemm_kernel<<<gemmBlocks, 256, 0, stream>>>(h, W3, cnt, g, N);
    agg_kernel<1><<<aggBlocks, 256, 0, stream>>>(g, cnt, adj, perm, b3, nullptr, out, N);
}

// Round 11
// 202.514 us; speedup vs baseline: 1.1125x; 1.1125x over previous
//
#include <hip/hip_runtime.h>
#include <hip/hip_bf16.h>

// ---------------------------------------------------------------------------
// GCN 3-layer, N=50000, E=800000, D=64, fp32 in/out.
// R11: exact R8 structure (measured best 198.6us; R7/R9/R10 agg restructures
// all regressed -> agg is miss-latency x concurrency bound). Deltas vs R8,
// confined to the agg inner loop: (1) adjacency indices loaded as int4
// (16->10 vmem instrs per 8-edge chunk), (2) residual row load hoisted above
// the gather loop to overlap its latency. MFMA gemm (R8), bucket adjacency
// (CAP 64 >> max deg ~38) + XCD-partitioned fill (R3/R4), bf16 table (R6).
// ---------------------------------------------------------------------------

#define CAP 64
#define EDGE_CHUNK 1024

typedef __attribute__((ext_vector_type(8))) short bf16x8;
typedef __attribute__((ext_vector_type(4))) float f32x4;

// --- pack two fp32 -> bf16x2 (RNE) ----------------------------------------
__device__ inline unsigned pack_bf16(float a, float b) {
    union { float f; unsigned i; } ua, ub;
    ua.f = a; ub.f = b;
    unsigned x = (ua.i + 0x7fffu + ((ua.i >> 16) & 1u)) >> 16;
    unsigned y = (ub.i + 0x7fffu + ((ub.i >> 16) & 1u)) >> 16;
    return x | (y << 16);
}
__device__ inline unsigned short to_bf16(float a) {
    union { float f; unsigned i; } u; u.f = a;
    return (unsigned short)((u.i + 0x7fffu + ((u.i >> 16) & 1u)) >> 16);
}
// --- accumulate bf16x2 (packed uint) into two floats ----------------------
__device__ inline void acc_bf16x2(unsigned u, float& a, float& b) {
    union { unsigned i; float f; } lo, hi;
    lo.i = u << 16;
    hi.i = u & 0xffff0000u;
    a += lo.f; b += hi.f;
}

// --- fused count+place: slot = atomicAdd(cnt), XCD-partitioned by dst -----
__global__ void fill_kernel(const int* __restrict__ src, const int* __restrict__ dst,
                            int* __restrict__ cnt, int* __restrict__ adj,
                            int E, int npc) {
    int cls = blockIdx.x & 7;          // -> XCD (round-robin heuristic)
    int base = (blockIdx.x >> 3) * EDGE_CHUNK;
    int end = min(base + EDGE_CHUNK, E);
    int lo = cls * npc, hi = lo + npc;
    for (int e = base + threadIdx.x; e < end; e += blockDim.x) {
        int d = dst[e];
        if (d >= lo && d < hi) {
            int p = atomicAdd(&cnt[d], 1);
            adj[(size_t)d * CAP + p] = src[e];
        }
    }
}

// --- g(bf16) = dinv ⊙ (in @ W) via MFMA; 64 rows/block, 4 waves -----------
__global__ __launch_bounds__(256) void gemm_kernel(const float* __restrict__ in,
                                                   const float* __restrict__ W,
                                                   const int* __restrict__ cnt,
                                                   unsigned short* __restrict__ g, int n) {
    __shared__ unsigned short Wb[512 * 8];  // B-frags: 8 (s,c) x 64 lanes x 8 bf16
    int t = threadIdx.x;

    // ---- stage W into B-fragment order (bf16) ----
#pragma unroll
    for (int e0 = 0; e0 < 2; e0++) {
        int e = t + e0 * 256;          // frag index 0..511
        int sc = e >> 6;               // s*4 + c
        int l  = e & 63;               // target lane
        int s = sc >> 2, c = sc & 3;
        int nn = c * 16 + (l & 15);
        int kb = s * 32 + (l >> 4) * 8;
        const float* wp = &W[(size_t)kb * 64 + nn];
        unsigned q0 = pack_bf16(wp[0 * 64], wp[1 * 64]);
        unsigned q1 = pack_bf16(wp[2 * 64], wp[3 * 64]);
        unsigned q2 = pack_bf16(wp[4 * 64], wp[5 * 64]);
        unsigned q3 = pack_bf16(wp[6 * 64], wp[7 * 64]);
        *(uint4*)&Wb[e * 8] = make_uint4(q0, q1, q2, q3);
    }

    int wv = t >> 6;
    int lane = t & 63;
    int quad = lane >> 4;
    int m16 = lane & 15;

    // ---- A fragments: row m16 of this wave's 16-row slab, k per quad ----
    int rowA = blockIdx.x * 64 + wv * 16 + m16;
    union { bf16x8 v; uint4 u; } a0, a1;
    {
        float4 f0 = make_float4(0, 0, 0, 0), f1 = f0, f2 = f0, f3 = f0;
        if (rowA < n) {
            const float* rp = &in[(size_t)rowA * 64];
            f0 = *(const float4*)&rp[quad * 8];
            f1 = *(const float4*)&rp[quad * 8 + 4];
            f2 = *(const float4*)&rp[32 + quad * 8];
            f3 = *(const float4*)&rp[32 + quad * 8 + 4];
        }
        a0.u = make_uint4(pack_bf16(f0.x, f0.y), pack_bf16(f0.z, f0.w),
                          pack_bf16(f1.x, f1.y), pack_bf16(f1.z, f1.w));
        a1.u = make_uint4(pack_bf16(f2.x, f2.y), pack_bf16(f2.z, f2.w),
                          pack_bf16(f3.x, f3.y), pack_bf16(f3.z, f3.w));
    }
    __syncthreads();

    // ---- 8 MFMAs: 4 col-tiles x 2 k-steps ----
    f32x4 acc[4];
#pragma unroll
    for (int c = 0; c < 4; c++) {
        bf16x8 b0 = *(const bf16x8*)&Wb[((size_t)(0 * 4 + c) * 64 + lane) * 8];
        bf16x8 b1 = *(const bf16x8*)&Wb[((size_t)(1 * 4 + c) * 64 + lane) * 8];
        f32x4 z = {0.f, 0.f, 0.f, 0.f};
        z = __builtin_amdgcn_mfma_f32_16x16x32_bf16(a0.v, b0, z, 0, 0, 0);
        z = __builtin_amdgcn_mfma_f32_16x16x32_bf16(a1.v, b1, z, 0, 0, 0);
        acc[c] = z;
    }

    // ---- epilogue: scale by dinv[row], store bf16 (C rows = quad*4+reg) ----
    int rowbase = blockIdx.x * 64 + wv * 16 + quad * 4;
    float dv[4];
#pragma unroll
    for (int r = 0; r < 4; r++) {
        int row = rowbase + r;
        dv[r] = (row < n) ? rsqrtf((float)(cnt[row] + 1)) : 0.f;
    }
#pragma unroll
    for (int c = 0; c < 4; c++) {
#pragma unroll
        for (int r = 0; r < 4; r++) {
            int row = rowbase + r;
            if (row < n)
                g[(size_t)row * 64 + c * 16 + m16] = to_bf16(acc[c][r] * dv[r]);
        }
    }
}

// --- aggregation (R8 form): 16 lanes/node (uint2 = 4 bf16), unroll-8 ------
// R11: int4 index loads (lst 16B-aligned: CAP=64, k%8==0/4), hoisted res.
// out[i] = dinv[i]*(g[i] + sum_nbr g[j]) + bias  (+relu+res for MODE 0)
template <int MODE>
__global__ __launch_bounds__(256) void agg_kernel(const unsigned short* __restrict__ g,
                                                  const int* __restrict__ cnt,
                                                  const int* __restrict__ adj,
                                                  const float* __restrict__ bias,
                                                  const float* __restrict__ res,
                                                  float* __restrict__ out, int n) {
    int t = threadIdx.x;
    int lg = t & 15;
    int i = blockIdx.x * 16 + (t >> 4);
    if (i >= n) return;
    int deg = cnt[i];
    const int* lst = adj + (size_t)i * CAP;
    const int c4 = lg * 4;
    // hoist the streaming residual load: overlaps the gather chain
    float4 rr = make_float4(0.f, 0.f, 0.f, 0.f);
    if (MODE == 0) rr = *(const float4*)&res[(size_t)i * 64 + c4];
    float ax = 0.f, ay = 0.f, az = 0.f, aw = 0.f;
    {   // self loop
        uint2 v = *(const uint2*)&g[(size_t)i * 64 + c4];
        acc_bf16x2(v.x, ax, ay);
        acc_bf16x2(v.y, az, aw);
    }
    int k = 0;
    for (; k + 8 <= deg; k += 8) {
        int4 ja = *(const int4*)&lst[k];      // 2 vector index loads
        int4 jb = *(const int4*)&lst[k + 4];  // (was 8 scalar loads)
        uint2 v0 = *(const uint2*)&g[(size_t)ja.x * 64 + c4];
        uint2 v1 = *(const uint2*)&g[(size_t)ja.y * 64 + c4];
        uint2 v2 = *(const uint2*)&g[(size_t)ja.z * 64 + c4];
        uint2 v3 = *(const uint2*)&g[(size_t)ja.w * 64 + c4];
        uint2 v4 = *(const uint2*)&g[(size_t)jb.x * 64 + c4];
        uint2 v5 = *(const uint2*)&g[(size_t)jb.y * 64 + c4];
        uint2 v6 = *(const uint2*)&g[(size_t)jb.z * 64 + c4];
        uint2 v7 = *(const uint2*)&g[(size_t)jb.w * 64 + c4];
        acc_bf16x2(v0.x, ax, ay); acc_bf16x2(v0.y, az, aw);
        acc_bf16x2(v1.x, ax, ay); acc_bf16x2(v1.y, az, aw);
        acc_bf16x2(v2.x, ax, ay); acc_bf16x2(v2.y, az, aw);
        acc_bf16x2(v3.x, ax, ay); acc_bf16x2(v3.y, az, aw);
        acc_bf16x2(v4.x, ax, ay); acc_bf16x2(v4.y, az, aw);
        acc_bf16x2(v5.x, ax, ay); acc_bf16x2(v5.y, az, aw);
        acc_bf16x2(v6.x, ax, ay); acc_bf16x2(v6.y, az, aw);
        acc_bf16x2(v7.x, ax, ay); acc_bf16x2(v7.y, az, aw);
    }
    if (k + 4 <= deg) {
        int4 ja = *(const int4*)&lst[k];
        uint2 v0 = *(const uint2*)&g[(size_t)ja.x * 64 + c4];
        uint2 v1 = *(const uint2*)&g[(size_t)ja.y * 64 + c4];
        uint2 v2 = *(const uint2*)&g[(size_t)ja.z * 64 + c4];
        uint2 v3 = *(const uint2*)&g[(size_t)ja.w * 64 + c4];
        acc_bf16x2(v0.x, ax, ay); acc_bf16x2(v0.y, az, aw);
        acc_bf16x2(v1.x, ax, ay); acc_bf16x2(v1.y, az, aw);
        acc_bf16x2(v2.x, ax, ay); acc_bf16x2(v2.y, az, aw);
        acc_bf16x2(v3.x, ax, ay); acc_bf16x2(v3.y, az, aw);
        k += 4;
    }
    for (; k < deg; k++) {
        uint2 v = *(const uint2*)&g[(size_t)lst[k] * 64 + c4];
        acc_bf16x2(v.x, ax, ay);
        acc_bf16x2(v.y, az, aw);
    }
    float dv = rsqrtf((float)(deg + 1));
    float4 bb = *(const float4*)&bias[c4];
    float4 v;
    v.x = dv * ax + bb.x;
    v.y = dv * ay + bb.y;
    v.z = dv * az + bb.z;
    v.w = dv * aw + bb.w;
    if (MODE == 0) {
        v.x = fmaxf(v.x, 0.f) + rr.x;
        v.y = fmaxf(v.y, 0.f) + rr.y;
        v.z = fmaxf(v.z, 0.f) + rr.z;
        v.w = fmaxf(v.w, 0.f) + rr.w;
    }
    *(float4*)&out[(size_t)i * 64 + c4] = v;
}

extern "C" void kernel_launch(void* const* d_in, const int* in_sizes, int n_in,
                              void* d_out, int out_size, void* d_ws, size_t ws_size,
                              hipStream_t stream) {
    const float* x  = (const float*)d_in[0];
    const int*   ei = (const int*)d_in[1];
    const float* W1 = (const float*)d_in[2];
    const float* b1 = (const float*)d_in[3];
    const float* W2 = (const float*)d_in[4];
    const float* b2 = (const float*)d_in[5];
    const float* W3 = (const float*)d_in[6];
    const float* b3 = (const float*)d_in[7];
    float* out = (float*)d_out;

    const int N = in_sizes[0] / 64;
    const int E = in_sizes[1] / 2;
    const int* src = ei;
    const int* dst = ei + E;
    const int npc = (N + 7) / 8;
    const int nEdgeChunks = (E + EDGE_CHUNK - 1) / EDGE_CHUNK;

    // workspace layout
    char* p = (char*)d_ws;
    int*            cnt = (int*)p;            p += ((N + 63) / 64) * 64 * 4;
    int*            adj = (int*)p;            p += ((size_t)N + 1) * CAP * 4;
    unsigned short* g   = (unsigned short*)p; p += (size_t)N * 64 * 2;
    float*          h   = (float*)p;          p += (size_t)N * 64 * 4;

    const int aggBlocks  = (N + 15) / 16;
    const int gemmBlocks = (N + 63) / 64;

    // --- bucket adjacency build (ws re-poisoned every call) ---
    hipMemsetAsync(cnt, 0, (size_t)N * 4, stream);
    fill_kernel<<<nEdgeChunks * 8, 256, 0, stream>>>(src, dst, cnt, adj, E, npc);

    // --- layer 1: h = relu(agg(dinv⊙(x@W1))) + x ---
    gemm_kernel<<<gemmBlocks, 256, 0, stream>>>(x, W1, cnt, g, N);
    agg_kernel<0><<<aggBlocks, 256, 0, stream>>>(g, cnt, adj, b1, x, h, N);

    // --- layer 2: h = relu(agg(dinv⊙(h@W2))) + h ---
    gemm_kernel<<<gemmBlocks, 256, 0, stream>>>(h, W2, cnt, g, N);
    agg_kernel<0><<<aggBlocks, 256, 0, stream>>>(g, cnt, adj, b2, h, h, N);

    // --- layer 3: out = agg(dinv⊙(h@W3)) ---
    gemm_kernel<<<gemmBlocks, 256, 0, stream>>>(h, W3, cnt, g, N);
    agg_kernel<1><<<aggBlocks, 256, 0, stream>>>(g, cnt, adj, b3, nullptr, out, N);
}

// Round 12
// 198.445 us; speedup vs baseline: 1.1353x; 1.0205x over previous
//
#include <hip/hip_runtime.h>
#include <hip/hip_bf16.h>

// ---------------------------------------------------------------------------
// GCN 3-layer, N=50000, E=800000, D=64, fp32 in/out.
// R12: R11 with ONE variable changed — agg payload granularity uint2(8B,
// 16 lanes/row) -> uint4(16B, 8 lanes/row). Doubles rows + cache lines in
// flight per vmem instruction (agg is miss-concurrency x L3-latency bound;
// R9/R10/R11 ruled out residency, divergence, issue count). R7's uint4
// attempt was confounded by NT stores (L2 bypass hurt next gemm) and shfl
// fan-out — both omitted here. MFMA gemm (R8), bucket adjacency CAP=64,
// XCD-partitioned fill (R3/R4), bf16 table (R6), int4 index loads (R11).
// ---------------------------------------------------------------------------

#define CAP 64
#define EDGE_CHUNK 1024

typedef __attribute__((ext_vector_type(8))) short bf16x8;
typedef __attribute__((ext_vector_type(4))) float f32x4;

// --- pack two fp32 -> bf16x2 (RNE) ----------------------------------------
__device__ inline unsigned pack_bf16(float a, float b) {
    union { float f; unsigned i; } ua, ub;
    ua.f = a; ub.f = b;
    unsigned x = (ua.i + 0x7fffu + ((ua.i >> 16) & 1u)) >> 16;
    unsigned y = (ub.i + 0x7fffu + ((ub.i >> 16) & 1u)) >> 16;
    return x | (y << 16);
}
__device__ inline unsigned short to_bf16(float a) {
    union { float f; unsigned i; } u; u.f = a;
    return (unsigned short)((u.i + 0x7fffu + ((u.i >> 16) & 1u)) >> 16);
}
// --- accumulate bf16x2 (packed uint) into two floats ----------------------
__device__ inline void acc_bf16x2(unsigned u, float& a, float& b) {
    union { unsigned i; float f; } lo, hi;
    lo.i = u << 16;
    hi.i = u & 0xffff0000u;
    a += lo.f; b += hi.f;
}

// --- fused count+place: slot = atomicAdd(cnt), XCD-partitioned by dst -----
__global__ void fill_kernel(const int* __restrict__ src, const int* __restrict__ dst,
                            int* __restrict__ cnt, int* __restrict__ adj,
                            int E, int npc) {
    int cls = blockIdx.x & 7;          // -> XCD (round-robin heuristic)
    int base = (blockIdx.x >> 3) * EDGE_CHUNK;
    int end = min(base + EDGE_CHUNK, E);
    int lo = cls * npc, hi = lo + npc;
    for (int e = base + threadIdx.x; e < end; e += blockDim.x) {
        int d = dst[e];
        if (d >= lo && d < hi) {
            int p = atomicAdd(&cnt[d], 1);
            adj[(size_t)d * CAP + p] = src[e];
        }
    }
}

// --- g(bf16) = dinv ⊙ (in @ W) via MFMA; 64 rows/block, 4 waves -----------
__global__ __launch_bounds__(256) void gemm_kernel(const float* __restrict__ in,
                                                   const float* __restrict__ W,
                                                   const int* __restrict__ cnt,
                                                   unsigned short* __restrict__ g, int n) {
    __shared__ unsigned short Wb[512 * 8];  // B-frags: 8 (s,c) x 64 lanes x 8 bf16
    int t = threadIdx.x;

    // ---- stage W into B-fragment order (bf16) ----
#pragma unroll
    for (int e0 = 0; e0 < 2; e0++) {
        int e = t + e0 * 256;          // frag index 0..511
        int sc = e >> 6;               // s*4 + c
        int l  = e & 63;               // target lane
        int s = sc >> 2, c = sc & 3;
        int nn = c * 16 + (l & 15);
        int kb = s * 32 + (l >> 4) * 8;
        const float* wp = &W[(size_t)kb * 64 + nn];
        unsigned q0 = pack_bf16(wp[0 * 64], wp[1 * 64]);
        unsigned q1 = pack_bf16(wp[2 * 64], wp[3 * 64]);
        unsigned q2 = pack_bf16(wp[4 * 64], wp[5 * 64]);
        unsigned q3 = pack_bf16(wp[6 * 64], wp[7 * 64]);
        *(uint4*)&Wb[e * 8] = make_uint4(q0, q1, q2, q3);
    }

    int wv = t >> 6;
    int lane = t & 63;
    int quad = lane >> 4;
    int m16 = lane & 15;

    // ---- A fragments: row m16 of this wave's 16-row slab, k per quad ----
    int rowA = blockIdx.x * 64 + wv * 16 + m16;
    union { bf16x8 v; uint4 u; } a0, a1;
    {
        float4 f0 = make_float4(0, 0, 0, 0), f1 = f0, f2 = f0, f3 = f0;
        if (rowA < n) {
            const float* rp = &in[(size_t)rowA * 64];
            f0 = *(const float4*)&rp[quad * 8];
            f1 = *(const float4*)&rp[quad * 8 + 4];
            f2 = *(const float4*)&rp[32 + quad * 8];
            f3 = *(const float4*)&rp[32 + quad * 8 + 4];
        }
        a0.u = make_uint4(pack_bf16(f0.x, f0.y), pack_bf16(f0.z, f0.w),
                          pack_bf16(f1.x, f1.y), pack_bf16(f1.z, f1.w));
        a1.u = make_uint4(pack_bf16(f2.x, f2.y), pack_bf16(f2.z, f2.w),
                          pack_bf16(f3.x, f3.y), pack_bf16(f3.z, f3.w));
    }
    __syncthreads();

    // ---- 8 MFMAs: 4 col-tiles x 2 k-steps ----
    f32x4 acc[4];
#pragma unroll
    for (int c = 0; c < 4; c++) {
        bf16x8 b0 = *(const bf16x8*)&Wb[((size_t)(0 * 4 + c) * 64 + lane) * 8];
        bf16x8 b1 = *(const bf16x8*)&Wb[((size_t)(1 * 4 + c) * 64 + lane) * 8];
        f32x4 z = {0.f, 0.f, 0.f, 0.f};
        z = __builtin_amdgcn_mfma_f32_16x16x32_bf16(a0.v, b0, z, 0, 0, 0);
        z = __builtin_amdgcn_mfma_f32_16x16x32_bf16(a1.v, b1, z, 0, 0, 0);
        acc[c] = z;
    }

    // ---- epilogue: scale by dinv[row], store bf16 (C rows = quad*4+reg) ----
    int rowbase = blockIdx.x * 64 + wv * 16 + quad * 4;
    float dv[4];
#pragma unroll
    for (int r = 0; r < 4; r++) {
        int row = rowbase + r;
        dv[r] = (row < n) ? rsqrtf((float)(cnt[row] + 1)) : 0.f;
    }
#pragma unroll
    for (int c = 0; c < 4; c++) {
#pragma unroll
        for (int r = 0; r < 4; r++) {
            int row = rowbase + r;
            if (row < n)
                g[(size_t)row * 64 + c * 16 + m16] = to_bf16(acc[c][r] * dv[r]);
        }
    }
}

// --- aggregation: 8 lanes/node (uint4 = 8 bf16 /lane), 8 nodes/wave -------
// int4 index loads, unroll-8 -> 64 rows (128 lines) in flight per wave.
// out[i] = dinv[i]*(g[i] + sum_nbr g[j]) + bias  (+relu+res for MODE 0)
template <int MODE>
__global__ __launch_bounds__(256) void agg_kernel(const unsigned short* __restrict__ g,
                                                  const int* __restrict__ cnt,
                                                  const int* __restrict__ adj,
                                                  const float* __restrict__ bias,
                                                  const float* __restrict__ res,
                                                  float* __restrict__ out, int n) {
    int t = threadIdx.x;
    int lg = t & 7;                    // lane within 8-lane node group
    int i = blockIdx.x * 32 + (t >> 3);
    if (i >= n) return;
    int deg = cnt[i];
    const int* lst = adj + (size_t)i * CAP;
    const int c8 = lg * 8;             // bf16 feature offset (16 B)
    size_t rowoff = (size_t)i * 64 + c8;
    // hoist the streaming residual load: overlaps the gather chain
    float4 r0 = make_float4(0.f, 0.f, 0.f, 0.f), r1 = r0;
    if (MODE == 0) {
        r0 = *(const float4*)&res[rowoff];
        r1 = *(const float4*)&res[rowoff + 4];
    }
    float a0 = 0.f, a1 = 0.f, a2 = 0.f, a3 = 0.f;
    float a4 = 0.f, a5 = 0.f, a6 = 0.f, a7 = 0.f;
    {   // self loop
        uint4 v = *(const uint4*)&g[(size_t)i * 64 + c8];
        acc_bf16x2(v.x, a0, a1); acc_bf16x2(v.y, a2, a3);
        acc_bf16x2(v.z, a4, a5); acc_bf16x2(v.w, a6, a7);
    }
    int k = 0;
    for (; k + 8 <= deg; k += 8) {
        int4 ja = *(const int4*)&lst[k];      // 2 vector index loads
        int4 jb = *(const int4*)&lst[k + 4];
        uint4 v0 = *(const uint4*)&g[(size_t)ja.x * 64 + c8];
        uint4 v1 = *(const uint4*)&g[(size_t)ja.y * 64 + c8];
        uint4 v2 = *(const uint4*)&g[(size_t)ja.z * 64 + c8];
        uint4 v3 = *(const uint4*)&g[(size_t)ja.w * 64 + c8];
        uint4 v4 = *(const uint4*)&g[(size_t)jb.x * 64 + c8];
        uint4 v5 = *(const uint4*)&g[(size_t)jb.y * 64 + c8];
        uint4 v6 = *(const uint4*)&g[(size_t)jb.z * 64 + c8];
        uint4 v7 = *(const uint4*)&g[(size_t)jb.w * 64 + c8];
        acc_bf16x2(v0.x, a0, a1); acc_bf16x2(v0.y, a2, a3);
        acc_bf16x2(v0.z, a4, a5); acc_bf16x2(v0.w, a6, a7);
        acc_bf16x2(v1.x, a0, a1); acc_bf16x2(v1.y, a2, a3);
        acc_bf16x2(v1.z, a4, a5); acc_bf16x2(v1.w, a6, a7);
        acc_bf16x2(v2.x, a0, a1); acc_bf16x2(v2.y, a2, a3);
        acc_bf16x2(v2.z, a4, a5); acc_bf16x2(v2.w, a6, a7);
        acc_bf16x2(v3.x, a0, a1); acc_bf16x2(v3.y, a2, a3);
        acc_bf16x2(v3.z, a4, a5); acc_bf16x2(v3.w, a6, a7);
        acc_bf16x2(v4.x, a0, a1); acc_bf16x2(v4.y, a2, a3);
        acc_bf16x2(v4.z, a4, a5); acc_bf16x2(v4.w, a6, a7);
        acc_bf16x2(v5.x, a0, a1); acc_bf16x2(v5.y, a2, a3);
        acc_bf16x2(v5.z, a4, a5); acc_bf16x2(v5.w, a6, a7);
        acc_bf16x2(v6.x, a0, a1); acc_bf16x2(v6.y, a2, a3);
        acc_bf16x2(v6.z, a4, a5); acc_bf16x2(v6.w, a6, a7);
        acc_bf16x2(v7.x, a0, a1); acc_bf16x2(v7.y, a2, a3);
        acc_bf16x2(v7.z, a4, a5); acc_bf16x2(v7.w, a6, a7);
    }
    if (k + 4 <= deg) {
        int4 ja = *(const int4*)&lst[k];
        uint4 v0 = *(const uint4*)&g[(size_t)ja.x * 64 + c8];
        uint4 v1 = *(const uint4*)&g[(size_t)ja.y * 64 + c8];
        uint4 v2 = *(const uint4*)&g[(size_t)ja.z * 64 + c8];
        uint4 v3 = *(const uint4*)&g[(size_t)ja.w * 64 + c8];
        acc_bf16x2(v0.x, a0, a1); acc_bf16x2(v0.y, a2, a3);
        acc_bf16x2(v0.z, a4, a5); acc_bf16x2(v0.w, a6, a7);
        acc_bf16x2(v1.x, a0, a1); acc_bf16x2(v1.y, a2, a3);
        acc_bf16x2(v1.z, a4, a5); acc_bf16x2(v1.w, a6, a7);
        acc_bf16x2(v2.x, a0, a1); acc_bf16x2(v2.y, a2, a3);
        acc_bf16x2(v2.z, a4, a5); acc_bf16x2(v2.w, a6, a7);
        acc_bf16x2(v3.x, a0, a1); acc_bf16x2(v3.y, a2, a3);
        acc_bf16x2(v3.z, a4, a5); acc_bf16x2(v3.w, a6, a7);
        k += 4;
    }
    for (; k < deg; k++) {
        uint4 v = *(const uint4*)&g[(size_t)lst[k] * 64 + c8];
        acc_bf16x2(v.x, a0, a1); acc_bf16x2(v.y, a2, a3);
        acc_bf16x2(v.z, a4, a5); acc_bf16x2(v.w, a6, a7);
    }
    float dv = rsqrtf((float)(deg + 1));
    float4 b0 = *(const float4*)&bias[c8];
    float4 b1 = *(const float4*)&bias[c8 + 4];
    float4 o0, o1;
    o0.x = dv * a0 + b0.x; o0.y = dv * a1 + b0.y;
    o0.z = dv * a2 + b0.z; o0.w = dv * a3 + b0.w;
    o1.x = dv * a4 + b1.x; o1.y = dv * a5 + b1.y;
    o1.z = dv * a6 + b1.z; o1.w = dv * a7 + b1.w;
    if (MODE == 0) {
        o0.x = fmaxf(o0.x, 0.f) + r0.x; o0.y = fmaxf(o0.y, 0.f) + r0.y;
        o0.z = fmaxf(o0.z, 0.f) + r0.z; o0.w = fmaxf(o0.w, 0.f) + r0.w;
        o1.x = fmaxf(o1.x, 0.f) + r1.x; o1.y = fmaxf(o1.y, 0.f) + r1.y;
        o1.z = fmaxf(o1.z, 0.f) + r1.z; o1.w = fmaxf(o1.w, 0.f) + r1.w;
    }
    *(float4*)&out[rowoff] = o0;
    *(float4*)&out[rowoff + 4] = o1;
}

extern "C" void kernel_launch(void* const* d_in, const int* in_sizes, int n_in,
                              void* d_out, int out_size, void* d_ws, size_t ws_size,
                              hipStream_t stream) {
    const float* x  = (const float*)d_in[0];
    const int*   ei = (const int*)d_in[1];
    const float* W1 = (const float*)d_in[2];
    const float* b1 = (const float*)d_in[3];
    const float* W2 = (const float*)d_in[4];
    const float* b2 = (const float*)d_in[5];
    const float* W3 = (const float*)d_in[6];
    const float* b3 = (const float*)d_in[7];
    float* out = (float*)d_out;

    const int N = in_sizes[0] / 64;
    const int E = in_sizes[1] / 2;
    const int* src = ei;
    const int* dst = ei + E;
    const int npc = (N + 7) / 8;
    const int nEdgeChunks = (E + EDGE_CHUNK - 1) / EDGE_CHUNK;

    // workspace layout
    char* p = (char*)d_ws;
    int*            cnt = (int*)p;            p += ((N + 63) / 64) * 64 * 4;
    int*            adj = (int*)p;            p += ((size_t)N + 1) * CAP * 4;
    unsigned short* g   = (unsigned short*)p; p += (size_t)N * 64 * 2;
    float*          h   = (float*)p;          p += (size_t)N * 64 * 4;

    const int aggBlocks  = (N + 31) / 32;
    const int gemmBlocks = (N + 63) / 64;

    // --- bucket adjacency build (ws re-poisoned every call) ---
    hipMemsetAsync(cnt, 0, (size_t)N * 4, stream);
    fill_kernel<<<nEdgeChunks * 8, 256, 0, stream>>>(src, dst, cnt, adj, E, npc);

    // --- layer 1: h = relu(agg(dinv⊙(x@W1))) + x ---
    gemm_kernel<<<gemmBlocks, 256, 0, stream>>>(x, W1, cnt, g, N);
    agg_kernel<0><<<aggBlocks, 256, 0, stream>>>(g, cnt, adj, b1, x, h, N);

    // --- layer 2: h = relu(agg(dinv⊙(h@W2))) + h ---
    gemm_kernel<<<gemmBlocks, 256, 0, stream>>>(h, W2, cnt, g, N);
    agg_kernel<0><<<aggBlocks, 256, 0, stream>>>(g, cnt, adj, b2, h, h, N);

    // --- layer 3: out = agg(dinv⊙(h@W3)) ---
    gemm_kernel<<<gemmBlocks, 256, 0, stream>>>(h, W3, cnt, g, N);
    agg_kernel<1><<<aggBlocks, 256, 0, stream>>>(g, cnt, adj, b3, nullptr, out, N);
}

// Round 13
// 195.493 us; speedup vs baseline: 1.1525x; 1.0151x over previous
//
#include <hip/hip_runtime.h>
#include <hip/hip_bf16.h>

// ---------------------------------------------------------------------------
// GCN 3-layer, N=50000, E=800000, D=64, fp32 in/out.
// R13: agg(l) + gemm(l+1) fused per 64-row block — the GEMM is row-local, so
// a block's freshly aggregated h rows feed its own MFMA tile through LDS
// A-fragments (conflict-free layout), never round-tripping h through HBM.
// Kills gemm2's h read and ALL of h2 (layer 3 has no residual): ~38 MB + 2
// launches. Agg inner loop = R8/R12 floor form (R9-R12 probe matrix: the
// gather is HW queue-bound; ~28us/layer is its floor). g double-buffered
// (fused kernel gathers g_l while writing g_{l+1}). MFMA gemm (R8), bucket
// adjacency CAP=64 + XCD-partitioned fill (R3/R4), bf16 table (R6).
// ---------------------------------------------------------------------------

#define CAP 64
#define EDGE_CHUNK 1024

typedef __attribute__((ext_vector_type(8))) short bf16x8;
typedef __attribute__((ext_vector_type(4))) float f32x4;

// --- pack two fp32 -> bf16x2 (RNE) ----------------------------------------
__device__ inline unsigned pack_bf16(float a, float b) {
    union { float f; unsigned i; } ua, ub;
    ua.f = a; ub.f = b;
    unsigned x = (ua.i + 0x7fffu + ((ua.i >> 16) & 1u)) >> 16;
    unsigned y = (ub.i + 0x7fffu + ((ub.i >> 16) & 1u)) >> 16;
    return x | (y << 16);
}
__device__ inline unsigned short to_bf16(float a) {
    union { float f; unsigned i; } u; u.f = a;
    return (unsigned short)((u.i + 0x7fffu + ((u.i >> 16) & 1u)) >> 16);
}
// --- accumulate bf16x2 (packed uint) into two floats ----------------------
__device__ inline void acc_bf16x2(unsigned u, float& a, float& b) {
    union { unsigned i; float f; } lo, hi;
    lo.i = u << 16;
    hi.i = u & 0xffff0000u;
    a += lo.f; b += hi.f;
}

// --- fused count+place: slot = atomicAdd(cnt), XCD-partitioned by dst -----
__global__ void fill_kernel(const int* __restrict__ src, const int* __restrict__ dst,
                            int* __restrict__ cnt, int* __restrict__ adj,
                            int E, int npc) {
    int cls = blockIdx.x & 7;          // -> XCD (round-robin heuristic)
    int base = (blockIdx.x >> 3) * EDGE_CHUNK;
    int end = min(base + EDGE_CHUNK, E);
    int lo = cls * npc, hi = lo + npc;
    for (int e = base + threadIdx.x; e < end; e += blockDim.x) {
        int d = dst[e];
        if (d >= lo && d < hi) {
            int p = atomicAdd(&cnt[d], 1);
            adj[(size_t)d * CAP + p] = src[e];
        }
    }
}

// --- stage W (fp32 64x64) into B-fragment order (bf16) in LDS -------------
__device__ inline void stage_W(const float* __restrict__ W, unsigned short* Wb, int t) {
#pragma unroll
    for (int e0 = 0; e0 < 2; e0++) {
        int e = t + e0 * 256;          // frag index 0..511
        int sc = e >> 6;               // s*4 + c
        int l  = e & 63;               // target lane
        int s = sc >> 2, c = sc & 3;
        int nn = c * 16 + (l & 15);
        int kb = s * 32 + (l >> 4) * 8;
        const float* wp = &W[(size_t)kb * 64 + nn];
        unsigned q0 = pack_bf16(wp[0 * 64], wp[1 * 64]);
        unsigned q1 = pack_bf16(wp[2 * 64], wp[3 * 64]);
        unsigned q2 = pack_bf16(wp[4 * 64], wp[5 * 64]);
        unsigned q3 = pack_bf16(wp[6 * 64], wp[7 * 64]);
        *(uint4*)&Wb[e * 8] = make_uint4(q0, q1, q2, q3);
    }
}

// --- g(bf16) = dinv ⊙ (in @ W) via MFMA; 64 rows/block (layer 1 only) -----
__global__ __launch_bounds__(256) void gemm_kernel(const float* __restrict__ in,
                                                   const float* __restrict__ W,
                                                   const int* __restrict__ cnt,
                                                   unsigned short* __restrict__ g, int n) {
    __shared__ unsigned short Wb[512 * 8];
    int t = threadIdx.x;
    stage_W(W, Wb, t);

    int wv = t >> 6;
    int lane = t & 63;
    int quad = lane >> 4;
    int m16 = lane & 15;

    int rowA = blockIdx.x * 64 + wv * 16 + m16;
    union { bf16x8 v; uint4 u; } a0, a1;
    {
        float4 f0 = make_float4(0, 0, 0, 0), f1 = f0, f2 = f0, f3 = f0;
        if (rowA < n) {
            const float* rp = &in[(size_t)rowA * 64];
            f0 = *(const float4*)&rp[quad * 8];
            f1 = *(const float4*)&rp[quad * 8 + 4];
            f2 = *(const float4*)&rp[32 + quad * 8];
            f3 = *(const float4*)&rp[32 + quad * 8 + 4];
        }
        a0.u = make_uint4(pack_bf16(f0.x, f0.y), pack_bf16(f0.z, f0.w),
                          pack_bf16(f1.x, f1.y), pack_bf16(f1.z, f1.w));
        a1.u = make_uint4(pack_bf16(f2.x, f2.y), pack_bf16(f2.z, f2.w),
                          pack_bf16(f3.x, f3.y), pack_bf16(f3.z, f3.w));
    }
    __syncthreads();

    f32x4 acc[4];
#pragma unroll
    for (int c = 0; c < 4; c++) {
        bf16x8 b0 = *(const bf16x8*)&Wb[((size_t)(0 * 4 + c) * 64 + lane) * 8];
        bf16x8 b1 = *(const bf16x8*)&Wb[((size_t)(1 * 4 + c) * 64 + lane) * 8];
        f32x4 z = {0.f, 0.f, 0.f, 0.f};
        z = __builtin_amdgcn_mfma_f32_16x16x32_bf16(a0.v, b0, z, 0, 0, 0);
        z = __builtin_amdgcn_mfma_f32_16x16x32_bf16(a1.v, b1, z, 0, 0, 0);
        acc[c] = z;
    }

    int rowbase = blockIdx.x * 64 + wv * 16 + quad * 4;
    float dv[4];
#pragma unroll
    for (int r = 0; r < 4; r++) {
        int row = rowbase + r;
        dv[r] = (row < n) ? rsqrtf((float)(cnt[row] + 1)) : 0.f;
    }
#pragma unroll
    for (int c = 0; c < 4; c++) {
#pragma unroll
        for (int r = 0; r < 4; r++) {
            int row = rowbase + r;
            if (row < n)
                g[(size_t)row * 64 + c * 16 + m16] = to_bf16(acc[c][r] * dv[r]);
        }
    }
}

// --- fused agg(l) + gemm(l+1); 64 nodes/block -----------------------------
// Phase A (4 passes x 16 nodes, 16 lanes/node): gather g_in rows, epilogue
// h = relu(dinv*sum + bias) + res; optionally write h; deposit h (bf16) into
// A-fragment LDS. Phase B: 8 MFMAs vs staged W; write g_out = dinv ⊙ (h@W).
// A-frag LDS slot (w*8+chunk)*16+m16 holds feats chunk*8..+7 of row w*16+m16;
// write banks np*4+(lg&1)*2 (2-way), read banks m16*4 (2-way) — both free.
template <int WRITE_H>
__global__ __launch_bounds__(256) void aggemm_kernel(
        const unsigned short* __restrict__ g_in,
        const int* __restrict__ cnt,
        const int* __restrict__ adj,
        const float* __restrict__ bias,
        const float* __restrict__ res,
        const float* __restrict__ W,
        float* __restrict__ h_out,
        unsigned short* __restrict__ g_out,
        int n) {
    __shared__ unsigned short Wb[512 * 8];     // 8 KB B-frags
    __shared__ unsigned short Afrag[512 * 8];  // 8 KB A-frags
    int t = threadIdx.x;
    stage_W(W, Wb, t);

    // ---- Phase A: aggregate 64 nodes in 4 passes of 16 ----
    int np = t >> 4;                   // node-in-pass (== m16 of target row)
    int lg = t & 15;
    const int c4 = lg * 4;
    int chunk = lg >> 1;               // 8-feat chunk 0..7
    int half  = lg & 1;
#pragma unroll 1
    for (int p = 0; p < 4; p++) {
        int i = blockIdx.x * 64 + p * 16 + np;
        float vx = 0.f, vy = 0.f, vz = 0.f, vw = 0.f;
        if (i < n) {
            int deg = cnt[i];
            const int* lst = adj + (size_t)i * CAP;
            float4 rr = *(const float4*)&res[(size_t)i * 64 + c4];  // hoisted
            float ax = 0.f, ay = 0.f, az = 0.f, aw = 0.f;
            {   // self loop
                uint2 v = *(const uint2*)&g_in[(size_t)i * 64 + c4];
                acc_bf16x2(v.x, ax, ay);
                acc_bf16x2(v.y, az, aw);
            }
            int k = 0;
            for (; k + 8 <= deg; k += 8) {
                int4 ja = *(const int4*)&lst[k];
                int4 jb = *(const int4*)&lst[k + 4];
                uint2 v0 = *(const uint2*)&g_in[(size_t)ja.x * 64 + c4];
                uint2 v1 = *(const uint2*)&g_in[(size_t)ja.y * 64 + c4];
                uint2 v2 = *(const uint2*)&g_in[(size_t)ja.z * 64 + c4];
                uint2 v3 = *(const uint2*)&g_in[(size_t)ja.w * 64 + c4];
                uint2 v4 = *(const uint2*)&g_in[(size_t)jb.x * 64 + c4];
                uint2 v5 = *(const uint2*)&g_in[(size_t)jb.y * 64 + c4];
                uint2 v6 = *(const uint2*)&g_in[(size_t)jb.z * 64 + c4];
                uint2 v7 = *(const uint2*)&g_in[(size_t)jb.w * 64 + c4];
                acc_bf16x2(v0.x, ax, ay); acc_bf16x2(v0.y, az, aw);
                acc_bf16x2(v1.x, ax, ay); acc_bf16x2(v1.y, az, aw);
                acc_bf16x2(v2.x, ax, ay); acc_bf16x2(v2.y, az, aw);
                acc_bf16x2(v3.x, ax, ay); acc_bf16x2(v3.y, az, aw);
                acc_bf16x2(v4.x, ax, ay); acc_bf16x2(v4.y, az, aw);
                acc_bf16x2(v5.x, ax, ay); acc_bf16x2(v5.y, az, aw);
                acc_bf16x2(v6.x, ax, ay); acc_bf16x2(v6.y, az, aw);
                acc_bf16x2(v7.x, ax, ay); acc_bf16x2(v7.y, az, aw);
            }
            if (k + 4 <= deg) {
                int4 ja = *(const int4*)&lst[k];
                uint2 v0 = *(const uint2*)&g_in[(size_t)ja.x * 64 + c4];
                uint2 v1 = *(const uint2*)&g_in[(size_t)ja.y * 64 + c4];
                uint2 v2 = *(const uint2*)&g_in[(size_t)ja.z * 64 + c4];
                uint2 v3 = *(const uint2*)&g_in[(size_t)ja.w * 64 + c4];
                acc_bf16x2(v0.x, ax, ay); acc_bf16x2(v0.y, az, aw);
                acc_bf16x2(v1.x, ax, ay); acc_bf16x2(v1.y, az, aw);
                acc_bf16x2(v2.x, ax, ay); acc_bf16x2(v2.y, az, aw);
                acc_bf16x2(v3.x, ax, ay); acc_bf16x2(v3.y, az, aw);
                k += 4;
            }
            for (; k < deg; k++) {
                uint2 v = *(const uint2*)&g_in[(size_t)lst[k] * 64 + c4];
                acc_bf16x2(v.x, ax, ay);
                acc_bf16x2(v.y, az, aw);
            }
            float dvv = rsqrtf((float)(deg + 1));
            float4 bb = *(const float4*)&bias[c4];
            vx = fmaxf(dvv * ax + bb.x, 0.f) + rr.x;
            vy = fmaxf(dvv * ay + bb.y, 0.f) + rr.y;
            vz = fmaxf(dvv * az + bb.z, 0.f) + rr.z;
            vw = fmaxf(dvv * aw + bb.w, 0.f) + rr.w;
            if (WRITE_H) {
                float4 hv = make_float4(vx, vy, vz, vw);
                *(float4*)&h_out[(size_t)i * 64 + c4] = hv;
            }
        }
        // deposit into A-frag LDS (zeros for i>=n)
        uint2 pk;
        pk.x = pack_bf16(vx, vy);
        pk.y = pack_bf16(vz, vw);
        *(uint2*)&Afrag[(((size_t)(p * 8 + chunk) * 16 + np) * 8) + half * 4] = pk;
    }
    __syncthreads();

    // ---- Phase B: MFMA gemm on the tile ----
    int wv = t >> 6;
    int lane = t & 63;
    int quad = lane >> 4;
    int m16 = lane & 15;
    bf16x8 a0 = *(const bf16x8*)&Afrag[((size_t)(wv * 8 + quad) * 16 + m16) * 8];
    bf16x8 a1 = *(const bf16x8*)&Afrag[((size_t)(wv * 8 + 4 + quad) * 16 + m16) * 8];
    f32x4 acc[4];
#pragma unroll
    for (int c = 0; c < 4; c++) {
        bf16x8 b0 = *(const bf16x8*)&Wb[((size_t)(0 * 4 + c) * 64 + lane) * 8];
        bf16x8 b1 = *(const bf16x8*)&Wb[((size_t)(1 * 4 + c) * 64 + lane) * 8];
        f32x4 z = {0.f, 0.f, 0.f, 0.f};
        z = __builtin_amdgcn_mfma_f32_16x16x32_bf16(a0, b0, z, 0, 0, 0);
        z = __builtin_amdgcn_mfma_f32_16x16x32_bf16(a1, b1, z, 0, 0, 0);
        acc[c] = z;
    }
    int rowbase = blockIdx.x * 64 + wv * 16 + quad * 4;
    float dv2[4];
#pragma unroll
    for (int r = 0; r < 4; r++) {
        int row = rowbase + r;
        dv2[r] = (row < n) ? rsqrtf((float)(cnt[row] + 1)) : 0.f;
    }
#pragma unroll
    for (int c = 0; c < 4; c++) {
#pragma unroll
        for (int r = 0; r < 4; r++) {
            int row = rowbase + r;
            if (row < n)
                g_out[(size_t)row * 64 + c * 16 + m16] = to_bf16(acc[c][r] * dv2[r]);
        }
    }
}

// --- final aggregation (R12 form): 8 lanes/node uint4, int4 indices -------
__global__ __launch_bounds__(256) void agg_kernel(const unsigned short* __restrict__ g,
                                                  const int* __restrict__ cnt,
                                                  const int* __restrict__ adj,
                                                  const float* __restrict__ bias,
                                                  float* __restrict__ out, int n) {
    int t = threadIdx.x;
    int lg = t & 7;
    int i = blockIdx.x * 32 + (t >> 3);
    if (i >= n) return;
    int deg = cnt[i];
    const int* lst = adj + (size_t)i * CAP;
    const int c8 = lg * 8;
    size_t rowoff = (size_t)i * 64 + c8;
    float a0 = 0.f, a1 = 0.f, a2 = 0.f, a3 = 0.f;
    float a4 = 0.f, a5 = 0.f, a6 = 0.f, a7 = 0.f;
    {   // self loop
        uint4 v = *(const uint4*)&g[(size_t)i * 64 + c8];
        acc_bf16x2(v.x, a0, a1); acc_bf16x2(v.y, a2, a3);
        acc_bf16x2(v.z, a4, a5); acc_bf16x2(v.w, a6, a7);
    }
    int k = 0;
    for (; k + 8 <= deg; k += 8) {
        int4 ja = *(const int4*)&lst[k];
        int4 jb = *(const int4*)&lst[k + 4];
        uint4 v0 = *(const uint4*)&g[(size_t)ja.x * 64 + c8];
        uint4 v1 = *(const uint4*)&g[(size_t)ja.y * 64 + c8];
        uint4 v2 = *(const uint4*)&g[(size_t)ja.z * 64 + c8];
        uint4 v3 = *(const uint4*)&g[(size_t)ja.w * 64 + c8];
        uint4 v4 = *(const uint4*)&g[(size_t)jb.x * 64 + c8];
        uint4 v5 = *(const uint4*)&g[(size_t)jb.y * 64 + c8];
        uint4 v6 = *(const uint4*)&g[(size_t)jb.z * 64 + c8];
        uint4 v7 = *(const uint4*)&g[(size_t)jb.w * 64 + c8];
        acc_bf16x2(v0.x, a0, a1); acc_bf16x2(v0.y, a2, a3);
        acc_bf16x2(v0.z, a4, a5); acc_bf16x2(v0.w, a6, a7);
        acc_bf16x2(v1.x, a0, a1); acc_bf16x2(v1.y, a2, a3);
        acc_bf16x2(v1.z, a4, a5); acc_bf16x2(v1.w, a6, a7);
        acc_bf16x2(v2.x, a0, a1); acc_bf16x2(v2.y, a2, a3);
        acc_bf16x2(v2.z, a4, a5); acc_bf16x2(v2.w, a6, a7);
        acc_bf16x2(v3.x, a0, a1); acc_bf16x2(v3.y, a2, a3);
        acc_bf16x2(v3.z, a4, a5); acc_bf16x2(v3.w, a6, a7);
        acc_bf16x2(v4.x, a0, a1); acc_bf16x2(v4.y, a2, a3);
        acc_bf16x2(v4.z, a4, a5); acc_bf16x2(v4.w, a6, a7);
        acc_bf16x2(v5.x, a0, a1); acc_bf16x2(v5.y, a2, a3);
        acc_bf16x2(v5.z, a4, a5); acc_bf16x2(v5.w, a6, a7);
        acc_bf16x2(v6.x, a0, a1); acc_bf16x2(v6.y, a2, a3);
        acc_bf16x2(v6.z, a4, a5); acc_bf16x2(v6.w, a6, a7);
        acc_bf16x2(v7.x, a0, a1); acc_bf16x2(v7.y, a2, a3);
        acc_bf16x2(v7.z, a4, a5); acc_bf16x2(v7.w, a6, a7);
    }
    if (k + 4 <= deg) {
        int4 ja = *(const int4*)&lst[k];
        uint4 v0 = *(const uint4*)&g[(size_t)ja.x * 64 + c8];
        uint4 v1 = *(const uint4*)&g[(size_t)ja.y * 64 + c8];
        uint4 v2 = *(const uint4*)&g[(size_t)ja.z * 64 + c8];
        uint4 v3 = *(const uint4*)&g[(size_t)ja.w * 64 + c8];
        acc_bf16x2(v0.x, a0, a1); acc_bf16x2(v0.y, a2, a3);
        acc_bf16x2(v0.z, a4, a5); acc_bf16x2(v0.w, a6, a7);
        acc_bf16x2(v1.x, a0, a1); acc_bf16x2(v1.y, a2, a3);
        acc_bf16x2(v1.z, a4, a5); acc_bf16x2(v1.w, a6, a7);
        acc_bf16x2(v2.x, a0, a1); acc_bf16x2(v2.y, a2, a3);
        acc_bf16x2(v2.z, a4, a5); acc_bf16x2(v2.w, a6, a7);
        acc_bf16x2(v3.x, a0, a1); acc_bf16x2(v3.y, a2, a3);
        acc_bf16x2(v3.z, a4, a5); acc_bf16x2(v3.w, a6, a7);
        k += 4;
    }
    for (; k < deg; k++) {
        uint4 v = *(const uint4*)&g[(size_t)lst[k] * 64 + c8];
        acc_bf16x2(v.x, a0, a1); acc_bf16x2(v.y, a2, a3);
        acc_bf16x2(v.z, a4, a5); acc_bf16x2(v.w, a6, a7);
    }
    float dv = rsqrtf((float)(deg + 1));
    float4 b0 = *(const float4*)&bias[c8];
    float4 b1 = *(const float4*)&bias[c8 + 4];
    float4 o0, o1;
    o0.x = dv * a0 + b0.x; o0.y = dv * a1 + b0.y;
    o0.z = dv * a2 + b0.z; o0.w = dv * a3 + b0.w;
    o1.x = dv * a4 + b1.x; o1.y = dv * a5 + b1.y;
    o1.z = dv * a6 + b1.z; o1.w = dv * a7 + b1.w;
    *(float4*)&out[rowoff] = o0;
    *(float4*)&out[rowoff + 4] = o1;
}

extern "C" void kernel_launch(void* const* d_in, const int* in_sizes, int n_in,
                              void* d_out, int out_size, void* d_ws, size_t ws_size,
                              hipStream_t stream) {
    const float* x  = (const float*)d_in[0];
    const int*   ei = (const int*)d_in[1];
    const float* W1 = (const float*)d_in[2];
    const float* b1 = (const float*)d_in[3];
    const float* W2 = (const float*)d_in[4];
    const float* b2 = (const float*)d_in[5];
    const float* W3 = (const float*)d_in[6];
    const float* b3 = (const float*)d_in[7];
    float* out = (float*)d_out;

    const int N = in_sizes[0] / 64;
    const int E = in_sizes[1] / 2;
    const int* src = ei;
    const int* dst = ei + E;
    const int npc = (N + 7) / 8;
    const int nEdgeChunks = (E + EDGE_CHUNK - 1) / EDGE_CHUNK;

    // workspace layout
    char* p = (char*)d_ws;
    int*            cnt = (int*)p;            p += ((N + 63) / 64) * 64 * 4;
    int*            adj = (int*)p;            p += ((size_t)N + 1) * CAP * 4;
    unsigned short* ga  = (unsigned short*)p; p += (size_t)N * 64 * 2;
    unsigned short* gb  = (unsigned short*)p; p += (size_t)N * 64 * 2;
    float*          h1  = (float*)p;          p += (size_t)N * 64 * 4;

    const int tileBlocks = (N + 63) / 64;   // gemm + aggemm
    const int aggBlocks  = (N + 31) / 32;   // final agg

    // --- bucket adjacency build (ws re-poisoned every call) ---
    hipMemsetAsync(cnt, 0, (size_t)N * 4, stream);
    fill_kernel<<<nEdgeChunks * 8, 256, 0, stream>>>(src, dst, cnt, adj, E, npc);

    // --- layer 1 gemm: ga = dinv ⊙ (x@W1) ---
    gemm_kernel<<<tileBlocks, 256, 0, stream>>>(x, W1, cnt, ga, N);
    // --- fused: h1 = relu(agg(ga))+x ; gb = dinv ⊙ (h1@W2) ---
    aggemm_kernel<1><<<tileBlocks, 256, 0, stream>>>(ga, cnt, adj, b1, x, W2, h1, gb, N);
    // --- fused: h2 = relu(agg(gb))+h1 (kept in-kernel) ; ga = dinv ⊙ (h2@W3) ---
    aggemm_kernel<0><<<tileBlocks, 256, 0, stream>>>(gb, cnt, adj, b2, h1, W3, nullptr, ga, N);
    // --- final: out = agg(ga) + b3 ---
    agg_kernel<<<aggBlocks, 256, 0, stream>>>(ga, cnt, adj, b3, out, N);
}